// Round 2
// baseline (56091.400 us; speedup 1.0000x reference)
//
#include <hip/hip_runtime.h>
#include <hip/hip_bf16.h>

#define N_NODES 16384
#define E_EDGESN (16384*32)
#define FEAT 512
#define EMB 256
#define HID 512
#define G4 2048      // 4*HID
#define XDIM 512     // 2*EMB
#define NWG 16
#define UPW 32       // hidden units per workgroup

typedef __attribute__((ext_vector_type(8))) short bf16x8;
typedef __attribute__((ext_vector_type(4))) float f32x4;

__device__ __forceinline__ float b2f(unsigned short u) {
  union { unsigned int i; float f; } v; v.i = ((unsigned int)u) << 16; return v.f;
}
__device__ __forceinline__ unsigned short f2b(float f) {
  union { float f; unsigned int i; } v; v.f = f;
  unsigned int x = v.i;
  unsigned int r = (x + 0x7FFFu + ((x >> 16) & 1u)) >> 16;
  return (unsigned short)r;
}
__device__ __forceinline__ float sigmoidf_(float x) { return 1.0f / (1.0f + __expf(-x)); }

// ---------------- K0: dtype detection ----------------
// Reads 1024 u32 words from W_ih. If data is bf16-packed, bits 14:7 of each
// word are the exponent field of the low-half bf16 -> narrow band [90,126]
// (weights ~U(-0.044,0.044)). If data is fp32, those bits are uniform
// mantissa bits (~14% band hit rate). Vote: >=512 hits => bf16.
__global__ __launch_bounds__(256) void k_detect(const unsigned* __restrict__ w,
                                                unsigned* __restrict__ flag) {
  __shared__ int cnt;
  if (threadIdx.x == 0) cnt = 0;
  __syncthreads();
  int hits = 0;
#pragma unroll
  for (int j = 0; j < 4; ++j) {
    unsigned wv = w[threadIdx.x * 4 + j];
    unsigned e = (wv >> 7) & 0xFFu;
    if ((e >= 90u && e <= 126u) || ((wv & 0xFFFFu) == 0u)) hits++;
  }
  atomicAdd(&cnt, hits);
  __syncthreads();
  if (threadIdx.x == 0) *flag = (cnt < 512) ? 1u : 0u;   // 1 = fp32 inputs
}

// ---------------- K1: canonicalize float tensor to bf16 ----------------
__global__ void k_convert(const void* __restrict__ src, unsigned short* __restrict__ dst,
                          int n, const unsigned* __restrict__ flag) {
  int i = blockIdx.x * blockDim.x + threadIdx.x;
  if (i >= n) return;
  if (*flag) dst[i] = f2b(((const float*)src)[i]);
  else       dst[i] = ((const unsigned short*)src)[i];
}

// ---------------- K2: tag histogram scatter ----------------
__global__ void k_hist(const int* __restrict__ nid, const int* __restrict__ ntag,
                       unsigned* __restrict__ hist) {
  int e = blockIdx.x * blockDim.x + threadIdx.x;
  if (e < E_EDGESN)
    atomicAdd(&hist[(size_t)nid[e] * FEAT + ntag[e]], 1u);
}

// ---------------- K3: build x = [node_emb | nb_emb] as bf16 ----------------
__global__ __launch_bounds__(256) void k_build_x(
    const int* __restrict__ tags, const unsigned* __restrict__ hist,
    const unsigned short* __restrict__ Wemb, const unsigned short* __restrict__ bemb,
    unsigned short* __restrict__ x) {
  __shared__ int f_lds[160];
  __shared__ float c_lds[160];
  __shared__ int nlist;
  int n = blockIdx.x, c = threadIdx.x;
  if (c == 0) nlist = 0;
  __syncthreads();
  for (int f = c; f < FEAT; f += 256) {
    unsigned cnt = hist[(size_t)n * FEAT + f];
    if (cnt) {
      int idx = atomicAdd(&nlist, 1);
      if (idx < 160) { f_lds[idx] = f; c_lds[idx] = (float)cnt; }
    }
  }
  __syncthreads();
  int m = nlist; if (m > 160) m = 160;
  float be = b2f(bemb[c]);
  int tg = tags[n];
  x[(size_t)n * XDIM + c] = f2b(b2f(Wemb[(size_t)tg * EMB + c]) + be);
  float acc = be;
  for (int j = 0; j < m; ++j)
    acc += c_lds[j] * b2f(Wemb[(size_t)f_lds[j] * EMB + c]);
  x[(size_t)n * XDIM + EMB + c] = f2b(acc);
}

// ---------------- K4: pre = x @ W_ih^T + b_lstm (MFMA bf16) ----------------
__global__ __launch_bounds__(256) void k_gemm_pre(
    const unsigned short* __restrict__ x, const unsigned short* __restrict__ Wih,
    const unsigned short* __restrict__ blstm, unsigned short* __restrict__ pre) {
  int wave = threadIdx.x >> 6, lane = threadIdx.x & 63;
  int row = lane & 15, quad = lane >> 4;
  int mband = blockIdx.y * 64 + wave * 16;
  int nbase = blockIdx.x * 128;
  f32x4 acc[8] = {};
  const unsigned short* ap = x + (size_t)(mband + row) * XDIM + quad * 8;
  const unsigned short* bp0 = Wih + (size_t)(nbase + row) * XDIM + quad * 8;
  for (int kc = 0; kc < 16; ++kc) {
    bf16x8 af = *(const bf16x8*)(ap + kc * 32);
#pragma unroll
    for (int nt = 0; nt < 8; ++nt) {
      bf16x8 bf = *(const bf16x8*)(bp0 + (size_t)nt * 16 * XDIM + kc * 32);
      acc[nt] = __builtin_amdgcn_mfma_f32_16x16x32_bf16(af, bf, acc[nt], 0, 0, 0);
    }
  }
#pragma unroll
  for (int nt = 0; nt < 8; ++nt) {
    int nn = nbase + nt * 16 + row;
    float bv = b2f(blstm[nn]);
#pragma unroll
    for (int i = 0; i < 4; ++i) {
      int mm = mband + quad * 4 + i;
      pre[(size_t)mm * G4 + nn] = f2b(acc[nt][i] + bv);
    }
  }
}

// ---------------- K5: persistent multi-workgroup LSTM scan ----------------
// 16 wgs x 512 threads. wg owns units [wg*32, wg*32+32) -> 128 gate rows.
// thread: rg = tid>>4 (4 rows), s = tid&15 (k-slice of 32).
// W_hh rows held as fp32 in registers (128 VGPR). h staged in LDS fp32.
__global__ __launch_bounds__(512, 2) void k_scan(
    const unsigned short* __restrict__ Whh, const unsigned short* __restrict__ pre,
    float* __restrict__ hbuf, unsigned* __restrict__ ctr, float* __restrict__ embed) {
  __shared__ float h_lds[HID];
  __shared__ float g_lds[128];
  int tid = threadIdx.x, wg = blockIdx.x;
  int rg = tid >> 4, s = tid & 15;

  int growA[4];
  float wreg[4][32];
#pragma unroll
  for (int rr = 0; rr < 4; ++rr) {
    int r = rg * 4 + rr;
    int grow = (r >> 5) * HID + wg * UPW + (r & 31);   // gate*512 + unit
    growA[rr] = grow;
    const unsigned short* wp = Whh + (size_t)grow * HID + s * 32;
#pragma unroll
    for (int i = 0; i < 32; ++i) wreg[rr][i] = b2f(wp[i]);
  }

  float pcur[4];
#pragma unroll
  for (int rr = 0; rr < 4; ++rr) pcur[rr] = b2f(pre[growA[rr]]);  // row t=0

  h_lds[tid] = 0.0f;
  float cstate = 0.0f, eacc = 0.0f;
  __syncthreads();

  for (int t = 0; t < N_NODES; ++t) {
    float a0 = 0.f, a1 = 0.f, a2 = 0.f, a3 = 0.f;
    const float4* hp = (const float4*)&h_lds[s * 32];
#pragma unroll
    for (int i = 0; i < 8; ++i) {
      float4 hv = hp[i];
      a0 += wreg[0][4*i]*hv.x + wreg[0][4*i+1]*hv.y + wreg[0][4*i+2]*hv.z + wreg[0][4*i+3]*hv.w;
      a1 += wreg[1][4*i]*hv.x + wreg[1][4*i+1]*hv.y + wreg[1][4*i+2]*hv.z + wreg[1][4*i+3]*hv.w;
      a2 += wreg[2][4*i]*hv.x + wreg[2][4*i+1]*hv.y + wreg[2][4*i+2]*hv.z + wreg[2][4*i+3]*hv.w;
      a3 += wreg[3][4*i]*hv.x + wreg[3][4*i+1]*hv.y + wreg[3][4*i+2]*hv.z + wreg[3][4*i+3]*hv.w;
    }
#pragma unroll
    for (int off = 1; off < 16; off <<= 1) {
      a0 += __shfl_xor(a0, off);
      a1 += __shfl_xor(a1, off);
      a2 += __shfl_xor(a2, off);
      a3 += __shfl_xor(a3, off);
    }
    if (s == 0) {
      g_lds[rg * 4 + 0] = a0 + pcur[0];
      g_lds[rg * 4 + 1] = a1 + pcur[1];
      g_lds[rg * 4 + 2] = a2 + pcur[2];
      g_lds[rg * 4 + 3] = a3 + pcur[3];
    }
    __syncthreads();
    if (tid < UPW) {
      float gi = sigmoidf_(g_lds[tid]);
      float gf = sigmoidf_(g_lds[32 + tid]);
      float gg = tanhf(g_lds[64 + tid]);
      float go = sigmoidf_(g_lds[96 + tid]);
      cstate = gf * cstate + gi * gg;
      float hn = go * tanhf(cstate);
      eacc += hn;
      __hip_atomic_store(&hbuf[((t + 1) & 1) * HID + wg * UPW + tid], hn,
                         __ATOMIC_RELEASE, __HIP_MEMORY_SCOPE_AGENT);
    }
    __syncthreads();
    if (tid == 0)
      __hip_atomic_fetch_add(ctr, 1u, __ATOMIC_ACQ_REL, __HIP_MEMORY_SCOPE_AGENT);
    // prefetch next pre row while other wgs arrive
    if (s == 0 && (t + 1) < N_NODES) {
#pragma unroll
      for (int rr = 0; rr < 4; ++rr)
        pcur[rr] = b2f(pre[(size_t)(t + 1) * G4 + growA[rr]]);
    }
    if (tid == 0) {
      unsigned target = (unsigned)(NWG * (t + 1));
      while (__hip_atomic_load(ctr, __ATOMIC_ACQUIRE, __HIP_MEMORY_SCOPE_AGENT) < target)
        __builtin_amdgcn_s_sleep(1);
    }
    __syncthreads();
    h_lds[tid] = __hip_atomic_load(&hbuf[((t + 1) & 1) * HID + tid],
                                   __ATOMIC_ACQUIRE, __HIP_MEMORY_SCOPE_AGENT);
    __syncthreads();
  }
  if (tid < UPW) embed[wg * UPW + tid] = eacc;
}

// ---------------- K6: MLP head + log_softmax ----------------
__global__ __launch_bounds__(512) void k_head(
    const float* __restrict__ embed, const unsigned short* __restrict__ W1,
    const unsigned short* __restrict__ b1, const unsigned short* __restrict__ W2,
    const unsigned short* __restrict__ b2, void* __restrict__ out,
    const unsigned* __restrict__ flag) {
  __shared__ float e_s[HID], h1_s[HID];
  __shared__ float lg[16];
  int tid = threadIdx.x;
  e_s[tid] = embed[tid];
  __syncthreads();
  float sum = b2f(b1[tid]);
  for (int i = 0; i < HID; ++i)
    sum += e_s[i] * b2f(W1[(size_t)i * HID + tid]);
  h1_s[tid] = fmaxf(sum, 0.0f);
  __syncthreads();
  if (tid < 10) {
    float l = b2f(b2[tid]);
    for (int j = 0; j < HID; ++j)
      l += h1_s[j] * b2f(W2[(size_t)j * 10 + tid]);
    lg[tid] = l;
  }
  __syncthreads();
  if (tid == 0) {
    float m = -1e30f;
    for (int c = 0; c < 10; ++c) m = fmaxf(m, lg[c]);
    float se = 0.f;
    for (int c = 0; c < 10; ++c) se += expf(lg[c] - m);
    float lse = m + logf(se);
    if (*flag) {
      for (int c = 0; c < 10; ++c) ((float*)out)[c] = lg[c] - lse;
    } else {
      for (int c = 0; c < 10; ++c) ((unsigned short*)out)[c] = f2b(lg[c] - lse);
    }
  }
}

extern "C" void kernel_launch(void* const* d_in, const int* in_sizes, int n_in,
                              void* d_out, int out_size, void* d_ws, size_t ws_size,
                              hipStream_t stream) {
  const int* node_tags = (const int*)d_in[0];
  const int* nid = (const int*)d_in[1];
  const int* ntag = (const int*)d_in[2];
  // d_in[3] = label, unused

  char* ws = (char*)d_ws;
  unsigned short* pre  = (unsigned short*)ws;                     // 67,108,864
  unsigned short* x    = (unsigned short*)(ws + 67108864);        // 16,777,216
  unsigned*       hist = (unsigned*)(ws + 83886080);              // 33,554,432
  char* tail = ws + 117440512;                                    // 8192
  float*    hbuf  = (float*)tail;                                 // 2*512*4
  unsigned* ctr   = (unsigned*)(tail + 4096);
  unsigned* flag  = (unsigned*)(tail + 4160);
  float*    embed = (float*)(tail + 4608);                        // 512*4
  char* wc = ws + 117448704;                                      // bf16 weight copies
  unsigned short* Wemb_c  = (unsigned short*)(wc);                // 131072 el
  unsigned short* bemb_c  = (unsigned short*)(wc + 262144);       // 256
  unsigned short* Wih_c   = (unsigned short*)(wc + 262656);       // 1048576
  unsigned short* Whh_c   = (unsigned short*)(wc + 2359808);      // 1048576
  unsigned short* blstm_c = (unsigned short*)(wc + 4456960);      // 2048
  unsigned short* W1_c    = (unsigned short*)(wc + 4461056);      // 262144
  unsigned short* b1_c    = (unsigned short*)(wc + 4985344);      // 512
  unsigned short* W2_c    = (unsigned short*)(wc + 4986368);      // 5120
  unsigned short* b2_c    = (unsigned short*)(wc + 4996608);      // 10

  // zero hist + tail (ws is poisoned 0xAA before every launch)
  hipMemsetAsync(hist, 0, 33554432 + 8192, stream);

  k_detect<<<1, 256, 0, stream>>>((const unsigned*)d_in[6], flag);

  struct { const void* s; unsigned short* d; int n; } cv[9] = {
    { d_in[4],  Wemb_c,  FEAT * EMB },
    { d_in[5],  bemb_c,  EMB },
    { d_in[6],  Wih_c,   G4 * XDIM },
    { d_in[7],  Whh_c,   G4 * HID },
    { d_in[8],  blstm_c, G4 },
    { d_in[9],  W1_c,    HID * HID },
    { d_in[10], b1_c,    HID },
    { d_in[11], W2_c,    HID * 10 },
    { d_in[12], b2_c,    10 },
  };
  for (int i = 0; i < 9; ++i)
    k_convert<<<(cv[i].n + 255) / 256, 256, 0, stream>>>(cv[i].s, cv[i].d, cv[i].n, flag);

  k_hist<<<E_EDGESN / 256, 256, 0, stream>>>(nid, ntag, hist);
  k_build_x<<<N_NODES, 256, 0, stream>>>(node_tags, hist, Wemb_c, bemb_c, x);
  k_gemm_pre<<<dim3(G4 / 128, N_NODES / 64), 256, 0, stream>>>(x, Wih_c, blstm_c, pre);
  k_scan<<<NWG, 512, 0, stream>>>(Whh_c, pre, hbuf, ctr, embed);
  k_head<<<1, 512, 0, stream>>>(embed, W1_c, b1_c, W2_c, b2_c, d_out, flag);
}

// Round 3
// 32831.250 us; speedup vs baseline: 1.7085x; 1.7085x over previous
//
#include <hip/hip_runtime.h>
#include <hip/hip_bf16.h>

#define N_NODES 16384
#define E_EDGESN (16384*32)
#define FEAT 512
#define EMB 256
#define HID 512
#define G4 2048      // 4*HID
#define XDIM 512     // 2*EMB
#define NWG 16
#define UPW 32       // hidden units per workgroup

typedef __attribute__((ext_vector_type(8))) short bf16x8;
typedef __attribute__((ext_vector_type(4))) float f32x4;

__device__ __forceinline__ float b2f(unsigned short u) {
  union { unsigned int i; float f; } v; v.i = ((unsigned int)u) << 16; return v.f;
}
__device__ __forceinline__ unsigned short f2b(float f) {
  union { float f; unsigned int i; } v; v.f = f;
  unsigned int x = v.i;
  unsigned int r = (x + 0x7FFFu + ((x >> 16) & 1u)) >> 16;
  return (unsigned short)r;
}
__device__ __forceinline__ float sigmoidf_(float x) { return 1.0f / (1.0f + __expf(-x)); }

// ---------------- K0: dtype detection (bf16 vs fp32 inputs) ----------------
__global__ __launch_bounds__(256) void k_detect(const unsigned* __restrict__ w,
                                                unsigned* __restrict__ flag) {
  __shared__ int cnt;
  if (threadIdx.x == 0) cnt = 0;
  __syncthreads();
  int hits = 0;
#pragma unroll
  for (int j = 0; j < 4; ++j) {
    unsigned wv = w[threadIdx.x * 4 + j];
    unsigned e = (wv >> 7) & 0xFFu;
    if ((e >= 90u && e <= 126u) || ((wv & 0xFFFFu) == 0u)) hits++;
  }
  atomicAdd(&cnt, hits);
  __syncthreads();
  if (threadIdx.x == 0) *flag = (cnt < 512) ? 1u : 0u;   // 1 = fp32 inputs
}

// ---------------- K1: canonicalize float tensor to bf16 ----------------
__global__ void k_convert(const void* __restrict__ src, unsigned short* __restrict__ dst,
                          int n, const unsigned* __restrict__ flag) {
  int i = blockIdx.x * blockDim.x + threadIdx.x;
  if (i >= n) return;
  if (*flag) dst[i] = f2b(((const float*)src)[i]);
  else       dst[i] = ((const unsigned short*)src)[i];
}

// ---------------- K2: tag histogram scatter ----------------
__global__ void k_hist(const int* __restrict__ nid, const int* __restrict__ ntag,
                       unsigned* __restrict__ hist) {
  int e = blockIdx.x * blockDim.x + threadIdx.x;
  if (e < E_EDGESN)
    atomicAdd(&hist[(size_t)nid[e] * FEAT + ntag[e]], 1u);
}

// ---------------- K3: build x = [node_emb | nb_emb] as bf16 ----------------
__global__ __launch_bounds__(256) void k_build_x(
    const int* __restrict__ tags, const unsigned* __restrict__ hist,
    const unsigned short* __restrict__ Wemb, const unsigned short* __restrict__ bemb,
    unsigned short* __restrict__ x) {
  __shared__ int f_lds[160];
  __shared__ float c_lds[160];
  __shared__ int nlist;
  int n = blockIdx.x, c = threadIdx.x;
  if (c == 0) nlist = 0;
  __syncthreads();
  for (int f = c; f < FEAT; f += 256) {
    unsigned cnt = hist[(size_t)n * FEAT + f];
    if (cnt) {
      int idx = atomicAdd(&nlist, 1);
      if (idx < 160) { f_lds[idx] = f; c_lds[idx] = (float)cnt; }
    }
  }
  __syncthreads();
  int m = nlist; if (m > 160) m = 160;
  float be = b2f(bemb[c]);
  int tg = tags[n];
  x[(size_t)n * XDIM + c] = f2b(b2f(Wemb[(size_t)tg * EMB + c]) + be);
  float acc = be;
  for (int j = 0; j < m; ++j)
    acc += c_lds[j] * b2f(Wemb[(size_t)f_lds[j] * EMB + c]);
  x[(size_t)n * XDIM + EMB + c] = f2b(acc);
}

// ---------------- K4: pre = x @ W_ih^T + b_lstm (MFMA bf16) ----------------
__global__ __launch_bounds__(256) void k_gemm_pre(
    const unsigned short* __restrict__ x, const unsigned short* __restrict__ Wih,
    const unsigned short* __restrict__ blstm, unsigned short* __restrict__ pre) {
  int wave = threadIdx.x >> 6, lane = threadIdx.x & 63;
  int row = lane & 15, quad = lane >> 4;
  int mband = blockIdx.y * 64 + wave * 16;
  int nbase = blockIdx.x * 128;
  f32x4 acc[8] = {};
  const unsigned short* ap = x + (size_t)(mband + row) * XDIM + quad * 8;
  const unsigned short* bp0 = Wih + (size_t)(nbase + row) * XDIM + quad * 8;
  for (int kc = 0; kc < 16; ++kc) {
    bf16x8 af = *(const bf16x8*)(ap + kc * 32);
#pragma unroll
    for (int nt = 0; nt < 8; ++nt) {
      bf16x8 bf = *(const bf16x8*)(bp0 + (size_t)nt * 16 * XDIM + kc * 32);
      acc[nt] = __builtin_amdgcn_mfma_f32_16x16x32_bf16(af, bf, acc[nt], 0, 0, 0);
    }
  }
#pragma unroll
  for (int nt = 0; nt < 8; ++nt) {
    int nn = nbase + nt * 16 + row;
    float bv = b2f(blstm[nn]);
#pragma unroll
    for (int i = 0; i < 4; ++i) {
      int mm = mband + quad * 4 + i;
      pre[(size_t)mm * G4 + nn] = f2b(acc[nt][i] + bv);
    }
  }
}

// ---------------- K5: persistent LSTM scan, data-in-tag broadcast ----------------
// 16 wgs x 512 threads. wg owns units [wg*32, wg*32+32) -> 128 gate rows.
// thread: rg = tid>>4 (4 rows), s = tid&15 (interleaved k pairs: k = 32j+2s+{0,1}).
// Cross-wg h exchange: each fp32 h split into two words, each = 16 data bits | 16-bit
// step tag. Relaxed agent-scope store/poll; freshness is in the word itself ->
// ONE coherence round trip per step (vs 3 with counter barrier).
// 2-slot ring is safe: a wg writes step t+2 only after reading all of t+1, and each
// chunk of t+1 was produced only after its owner read all of t.
__global__ __launch_bounds__(512, 2) void k_scan(
    const unsigned short* __restrict__ Whh, const unsigned short* __restrict__ pre,
    unsigned* __restrict__ hw, float* __restrict__ embed) {
  __shared__ float h_lds[HID];
  __shared__ float g_lds[128];
  int tid = threadIdx.x, wg = blockIdx.x;
  int rg = tid >> 4, s = tid & 15;

  int growA[4];
  float wreg[4][32];
#pragma unroll
  for (int rr = 0; rr < 4; ++rr) {
    int r = rg * 4 + rr;
    int grow = (r >> 5) * HID + wg * UPW + (r & 31);   // gate*512 + unit
    growA[rr] = grow;
    const unsigned short* wp = Whh + (size_t)grow * HID;
#pragma unroll
    for (int j = 0; j < 16; ++j) {
      wreg[rr][2 * j]     = b2f(wp[32 * j + 2 * s]);
      wreg[rr][2 * j + 1] = b2f(wp[32 * j + 2 * s + 1]);
    }
  }

  float pcur[4];
#pragma unroll
  for (int rr = 0; rr < 4; ++rr) pcur[rr] = b2f(pre[growA[rr]]);  // row t=0

  h_lds[tid] = 0.0f;
  float cstate = 0.0f, eacc = 0.0f;
  __syncthreads();

  for (int t = 0; t < N_NODES; ++t) {
    // ---- matvec: a[rr] = sum_k W[row][k] * h[k], k = 32j + 2s + {0,1} ----
    float a0 = 0.f, a1 = 0.f, a2 = 0.f, a3 = 0.f;
    const float2* hb = (const float2*)h_lds;
#pragma unroll
    for (int j = 0; j < 16; ++j) {
      float2 hv = hb[j * 16 + s];   // banks {2s,2s+1}: conflict-free, 4-way bcast
      a0 += wreg[0][2*j] * hv.x + wreg[0][2*j+1] * hv.y;
      a1 += wreg[1][2*j] * hv.x + wreg[1][2*j+1] * hv.y;
      a2 += wreg[2][2*j] * hv.x + wreg[2][2*j+1] * hv.y;
      a3 += wreg[3][2*j] * hv.x + wreg[3][2*j+1] * hv.y;
    }
#pragma unroll
    for (int off = 1; off < 16; off <<= 1) {
      a0 += __shfl_xor(a0, off);
      a1 += __shfl_xor(a1, off);
      a2 += __shfl_xor(a2, off);
      a3 += __shfl_xor(a3, off);
    }
    if (s == 0) {
      g_lds[rg * 4 + 0] = a0 + pcur[0];
      g_lds[rg * 4 + 1] = a1 + pcur[1];
      g_lds[rg * 4 + 2] = a2 + pcur[2];
      g_lds[rg * 4 + 3] = a3 + pcur[3];
    }
    __syncthreads();   // (A)

    unsigned tagw = (unsigned)t & 0xFFFFu;
    unsigned base = ((unsigned)t & 1u) * 1024u;
    if (tid < UPW) {
      float gi = sigmoidf_(g_lds[tid]);
      float gf = sigmoidf_(g_lds[32 + tid]);
      float gg = tanhf(g_lds[64 + tid]);
      float go = sigmoidf_(g_lds[96 + tid]);
      cstate = gf * cstate + gi * gg;
      float hn = go * tanhf(cstate);
      eacc += hn;
      union { float f; unsigned u; } cu; cu.f = hn;
      __hip_atomic_store(&hw[base + wg * UPW + tid], (cu.u & 0xFFFF0000u) | tagw,
                         __ATOMIC_RELAXED, __HIP_MEMORY_SCOPE_AGENT);
      __hip_atomic_store(&hw[base + 512 + wg * UPW + tid], (cu.u << 16) | tagw,
                         __ATOMIC_RELAXED, __HIP_MEMORY_SCOPE_AGENT);
    }
    // prefetch next pre row (off critical path)
    if (s == 0 && (t + 1) < N_NODES) {
#pragma unroll
      for (int rr = 0; rr < 4; ++rr)
        pcur[rr] = b2f(pre[(size_t)(t + 1) * G4 + growA[rr]]);
    }
    if (t < N_NODES - 1) {
      unsigned v0, v1;
      for (;;) {
        v0 = __hip_atomic_load(&hw[base + tid],       __ATOMIC_RELAXED, __HIP_MEMORY_SCOPE_AGENT);
        v1 = __hip_atomic_load(&hw[base + 512 + tid], __ATOMIC_RELAXED, __HIP_MEMORY_SCOPE_AGENT);
        if ((((v0 ^ tagw) | (v1 ^ tagw)) & 0xFFFFu) == 0u) break;
        __builtin_amdgcn_s_sleep(1);
      }
      union { unsigned u; float f; } rc; rc.u = (v0 & 0xFFFF0000u) | (v1 >> 16);
      h_lds[tid] = rc.f;
      __syncthreads();   // (B)
    }
  }
  if (tid < UPW) embed[wg * UPW + tid] = eacc;
}

// ---------------- K6: MLP head + log_softmax ----------------
__global__ __launch_bounds__(512) void k_head(
    const float* __restrict__ embed, const unsigned short* __restrict__ W1,
    const unsigned short* __restrict__ b1, const unsigned short* __restrict__ W2,
    const unsigned short* __restrict__ b2, void* __restrict__ out,
    const unsigned* __restrict__ flag) {
  __shared__ float e_s[HID], h1_s[HID];
  __shared__ float lg[16];
  int tid = threadIdx.x;
  e_s[tid] = embed[tid];
  __syncthreads();
  float sum = b2f(b1[tid]);
  for (int i = 0; i < HID; ++i)
    sum += e_s[i] * b2f(W1[(size_t)i * HID + tid]);
  h1_s[tid] = fmaxf(sum, 0.0f);
  __syncthreads();
  if (tid < 10) {
    float l = b2f(b2[tid]);
    for (int j = 0; j < HID; ++j)
      l += h1_s[j] * b2f(W2[(size_t)j * 10 + tid]);
    lg[tid] = l;
  }
  __syncthreads();
  if (tid == 0) {
    float m = -1e30f;
    for (int c = 0; c < 10; ++c) m = fmaxf(m, lg[c]);
    float se = 0.f;
    for (int c = 0; c < 10; ++c) se += expf(lg[c] - m);
    float lse = m + logf(se);
    if (*flag) {
      for (int c = 0; c < 10; ++c) ((float*)out)[c] = lg[c] - lse;
    } else {
      for (int c = 0; c < 10; ++c) ((unsigned short*)out)[c] = f2b(lg[c] - lse);
    }
  }
}

extern "C" void kernel_launch(void* const* d_in, const int* in_sizes, int n_in,
                              void* d_out, int out_size, void* d_ws, size_t ws_size,
                              hipStream_t stream) {
  const int* node_tags = (const int*)d_in[0];
  const int* nid = (const int*)d_in[1];
  const int* ntag = (const int*)d_in[2];
  // d_in[3] = label, unused

  char* ws = (char*)d_ws;
  unsigned short* pre  = (unsigned short*)ws;                     // 67,108,864
  unsigned short* x    = (unsigned short*)(ws + 67108864);        // 16,777,216
  unsigned*       hist = (unsigned*)(ws + 83886080);              // 33,554,432
  char* tail = ws + 117440512;
  unsigned* hw    = (unsigned*)tail;                              // 2 slots * 1024 words = 8192 B (NOT zeroed: poison tag 0xAAAA is never valid)
  unsigned* flag  = (unsigned*)(tail + 8192);
  float*    embed = (float*)(tail + 8448);                        // 2048 B
  char* wc = ws + 117456896;                                      // bf16 weight copies
  unsigned short* Wemb_c  = (unsigned short*)(wc);                // 131072 el
  unsigned short* bemb_c  = (unsigned short*)(wc + 262144);       // 256
  unsigned short* Wih_c   = (unsigned short*)(wc + 262656);       // 1048576
  unsigned short* Whh_c   = (unsigned short*)(wc + 2359808);      // 1048576
  unsigned short* blstm_c = (unsigned short*)(wc + 4456960);      // 2048
  unsigned short* W1_c    = (unsigned short*)(wc + 4461056);      // 262144
  unsigned short* b1_c    = (unsigned short*)(wc + 4985344);      // 512
  unsigned short* W2_c    = (unsigned short*)(wc + 4986368);      // 5120
  unsigned short* b2_c    = (unsigned short*)(wc + 4996608);      // 10

  hipMemsetAsync(hist, 0, 33554432, stream);   // hist must start at zero

  k_detect<<<1, 256, 0, stream>>>((const unsigned*)d_in[6], flag);

  struct { const void* s; unsigned short* d; int n; } cv[9] = {
    { d_in[4],  Wemb_c,  FEAT * EMB },
    { d_in[5],  bemb_c,  EMB },
    { d_in[6],  Wih_c,   G4 * XDIM },
    { d_in[7],  Whh_c,   G4 * HID },
    { d_in[8],  blstm_c, G4 },
    { d_in[9],  W1_c,    HID * HID },
    { d_in[10], b1_c,    HID },
    { d_in[11], W2_c,    HID * 10 },
    { d_in[12], b2_c,    10 },
  };
  for (int i = 0; i < 9; ++i)
    k_convert<<<(cv[i].n + 255) / 256, 256, 0, stream>>>(cv[i].s, cv[i].d, cv[i].n, flag);

  k_hist<<<E_EDGESN / 256, 256, 0, stream>>>(nid, ntag, hist);
  k_build_x<<<N_NODES, 256, 0, stream>>>(node_tags, hist, Wemb_c, bemb_c, x);
  k_gemm_pre<<<dim3(G4 / 128, N_NODES / 64), 256, 0, stream>>>(x, Wih_c, blstm_c, pre);
  k_scan<<<NWG, 512, 0, stream>>>(Whh_c, pre, hw, embed);
  k_head<<<1, 512, 0, stream>>>(embed, W1_c, b1_c, W2_c, b2_c, d_out, flag);
}